// Round 3
// baseline (114.576 us; speedup 1.0000x reference)
//
#include <hip/hip_runtime.h>
#include <math.h>

static constexpr int M = 4096;   // batch rows
static constexpr int C = 512;    // classes
static constexpr int D = 128;    // feature dim
static constexpr float ALPHA = 0.5f;

// ---------------- workspace layout (bytes) ----------------
// label    : int[M]      @ 0      (16384)  fully written by k_labelinit
// zero region (zeroed by k_labelinit, accumulated by k_fused):
//   d_pos    : float[M]  @ 16384  (16384)
//   loss_sum : float[M]  @ 32768  (16384)
//   tile_cnt : uint[64]  @ 49152  (256)
static constexpr size_t WS_LABEL = 0;
static constexpr size_t WS_ZERO  = 16384;            // zero span start
static constexpr int    N_ZERO   = M + M + 64;       // 8256 words
static constexpr size_t WS_DPOS  = 16384;
static constexpr size_t WS_LSUM  = 32768;
static constexpr size_t WS_TCNT  = 49152;

// ---- kernel A: per-row argmax of onehot -> label[M]; zero accumulators ----
// one wave per row; 4 rows per 256-thread block; no atomics
__global__ __launch_bounds__(256) void k_labelinit(
    const float* __restrict__ onehot, int* __restrict__ label,
    float* __restrict__ zeros)
{
    int gtid = blockIdx.x * 256 + threadIdx.x;
    if (gtid < N_ZERO) zeros[gtid] = 0.0f;

    int row  = gtid >> 6;
    int lane = threadIdx.x & 63;
    if (row >= M) return;

    const float4* oh = reinterpret_cast<const float4*>(onehot + (size_t)row * C);
    float4 a = oh[lane * 2 + 0];
    float4 b = oh[lane * 2 + 1];
    int lbl = -1;
    if (a.x > 0.5f) lbl = lane * 8 + 0;
    if (a.y > 0.5f) lbl = lane * 8 + 1;
    if (a.z > 0.5f) lbl = lane * 8 + 2;
    if (a.w > 0.5f) lbl = lane * 8 + 3;
    if (b.x > 0.5f) lbl = lane * 8 + 4;
    if (b.y > 0.5f) lbl = lane * 8 + 5;
    if (b.z > 0.5f) lbl = lane * 8 + 6;
    if (b.w > 0.5f) lbl = lane * 8 + 7;
    #pragma unroll
    for (int off = 32; off > 0; off >>= 1)
        lbl = max(lbl, __shfl_xor(lbl, off));
    if (lane == 0) label[row] = lbl;
}

// ---- kernel B: fused {center update for class b} + {L1 distance tile b}
//      + last-block-per-m-tile loss finalize ----
// grid = 512 blocks x 256 threads (2 blocks/CU).
__global__ __launch_bounds__(256) void k_fused(
    const float* __restrict__ x0, const float* __restrict__ centers,
    const int* __restrict__ label,
    float* __restrict__ d_pos, float* __restrict__ loss_sum,
    unsigned int* __restrict__ tile_cnt,
    float* __restrict__ out_nc, float* __restrict__ loss_out)
{
    constexpr int BM = 64, DK = 64, STR = 68;
    __shared__ float xs[DK][STR];
    __shared__ float cs[DK][STR];
    __shared__ int   list[1024];
    __shared__ float tmp[128];
    __shared__ int   lcount;
    __shared__ int   lastflag;

    int tid = threadIdx.x;
    int b   = blockIdx.x;

    // ===== phase 1: center update for class c = b =====
    if (tid == 0) lcount = 0;
    __syncthreads();
    {
        const int4* lab4 = reinterpret_cast<const int4*>(label);
        #pragma unroll
        for (int t = 0; t < 4; ++t) {
            int4 v   = lab4[tid + 256 * t];
            int base = (tid + 256 * t) * 4;
            if (v.x == b) { int k = atomicAdd(&lcount, 1); if (k < 1024) list[k] = base + 0; }
            if (v.y == b) { int k = atomicAdd(&lcount, 1); if (k < 1024) list[k] = base + 1; }
            if (v.z == b) { int k = atomicAdd(&lcount, 1); if (k < 1024) list[k] = base + 2; }
            if (v.w == b) { int k = atomicAdd(&lcount, 1); if (k < 1024) list[k] = base + 3; }
        }
    }
    __syncthreads();
    {
        int n = lcount;
        int d    = tid & 127;            // feature
        int half = tid >> 7;             // 0/1: even/odd members
        float s = 0.f;
        for (int i = half; i < n; i += 2)
            s += x0[(size_t)list[i] * D + d];     // coalesced across d
        if (half == 1) tmp[d] = s;
        __syncthreads();
        if (half == 0) {
            s += tmp[d];
            float ctr = centers[b * D + d];
            out_nc[b * D + d] = ctr - ALPHA * ((float)n * ctr - s) / ((float)n + 1.0f);
        }
    }

    // ===== phase 2: L1-distance tile (mb, cb) =====
    int mb = b & 63;    // m tile
    int cb = b >> 6;    // c chunk
    int m0 = mb * BM, c0 = cb * BM;
    int tx = tid & 15;  // -> 4 c each
    int ty = tid >> 4;  // -> 4 m each

    float acc[4][4];
    #pragma unroll
    for (int i = 0; i < 4; i++)
        #pragma unroll
        for (int j = 0; j < 4; j++) acc[i][j] = 0.f;

    int lrow = tid >> 2;   // 0..63 : row of staged tile
    int dg   = tid & 3;    // 0..3  : 16-d group

    for (int dc = 0; dc < 2; ++dc) {
        int d0 = dc * DK;
        __syncthreads();   // also separates phase-1 LDS traffic
        {
            const float4* p = reinterpret_cast<const float4*>(
                x0 + (size_t)(m0 + lrow) * D + d0 + dg * 16);
            float4 v0 = p[0], v1 = p[1], v2 = p[2], v3 = p[3];
            float f[16] = {v0.x,v0.y,v0.z,v0.w, v1.x,v1.y,v1.z,v1.w,
                           v2.x,v2.y,v2.z,v2.w, v3.x,v3.y,v3.z,v3.w};
            int db = dg * 16;
            #pragma unroll
            for (int k = 0; k < 16; ++k) xs[db + k][lrow] = f[k];
        }
        {
            const float4* p = reinterpret_cast<const float4*>(
                centers + (size_t)(c0 + lrow) * D + d0 + dg * 16);
            float4 v0 = p[0], v1 = p[1], v2 = p[2], v3 = p[3];
            float f[16] = {v0.x,v0.y,v0.z,v0.w, v1.x,v1.y,v1.z,v1.w,
                           v2.x,v2.y,v2.z,v2.w, v3.x,v3.y,v3.z,v3.w};
            int db = dg * 16;
            #pragma unroll
            for (int k = 0; k < 16; ++k) cs[db + k][lrow] = f[k];
        }
        __syncthreads();

        #pragma unroll 8
        for (int d = 0; d < DK; ++d) {
            float4 xv = *reinterpret_cast<const float4*>(&xs[d][ty * 4]);
            float4 cv = *reinterpret_cast<const float4*>(&cs[d][tx * 4]);
            float xa[4] = {xv.x, xv.y, xv.z, xv.w};
            float ca[4] = {cv.x, cv.y, cv.z, cv.w};
            #pragma unroll
            for (int i = 0; i < 4; i++)
                #pragma unroll
                for (int j = 0; j < 4; j++)
                    acc[i][j] += fabsf(xa[i] - ca[j]);   // v_sub + v_add(|mod|)
        }
    }

    // epilogue: positive-class distance + per-chunk exp-sum partials (atomics)
    {
        int lbls[4];
        #pragma unroll
        for (int i = 0; i < 4; i++) lbls[i] = label[m0 + ty * 4 + i];

        #pragma unroll
        for (int i = 0; i < 4; i++) {
            float ps = 0.f;
            #pragma unroll
            for (int j = 0; j < 4; j++) {
                int cg = c0 + tx * 4 + j;
                float dist = acc[i][j];
                if (cg == lbls[i]) {
                    atomicAdd(&d_pos[m0 + ty * 4 + i], dist);  // unique contributor
                } else {
                    ps += __expf(-dist);
                }
            }
            // butterfly over the 16-lane tx group (intra-wave)
            #pragma unroll
            for (int off = 8; off > 0; off >>= 1)
                ps += __shfl_xor(ps, off);
            if (tx == 0)
                atomicAdd(&loss_sum[m0 + ty * 4 + i], ps);
        }
    }

    // ===== phase 3: last block of this m-tile finalizes the 64 losses =====
    __threadfence();          // order each thread's atomics before arrival
    __syncthreads();          // all threads arrived
    if (tid == 0) {
        unsigned int old = atomicAdd(&tile_cnt[mb], 1u);
        lastflag = (old == 7u) ? 1 : 0;
    }
    __syncthreads();
    if (lastflag) {
        __threadfence();      // acquire: see other blocks' atomics
        if (tid < BM) {
            int m = m0 + tid;
            float S  = atomicAdd(&loss_sum[m], 0.0f);  // coherent read
            float dp = atomicAdd(&d_pos[m],   0.0f);
            loss_out[m] = dp + log1pf(S);
        }
    }
}

extern "C" void kernel_launch(void* const* d_in, const int* in_sizes, int n_in,
                              void* d_out, int out_size, void* d_ws, size_t ws_size,
                              hipStream_t stream)
{
    const float* x0      = (const float*)d_in[0];   // (M, D)
    const float* onehot  = (const float*)d_in[1];   // (M, C)
    const float* centers = (const float*)d_in[2];   // (C, D)
    float* out = (float*)d_out;                     // [0..M) loss, [M..) new_centers

    char* ws = (char*)d_ws;
    int*          label    = (int*)          (ws + WS_LABEL);
    float*        zeros    = (float*)        (ws + WS_ZERO);
    float*        d_pos    = (float*)        (ws + WS_DPOS);
    float*        loss_sum = (float*)        (ws + WS_LSUM);
    unsigned int* tile_cnt = (unsigned int*) (ws + WS_TCNT);

    k_labelinit<<<M / 4, 256, 0, stream>>>(onehot, label, zeros);
    k_fused    <<<512,   256, 0, stream>>>(x0, centers, label, d_pos, loss_sum,
                                           tile_cnt, out + M, out);
}